// Round 2
// baseline (500.319 us; speedup 1.0000x reference)
//
#include <hip/hip_runtime.h>

#define NQ      14
#define NSTATE  16384   // 2^14
#define BLOCK   256
#define K_ITERS (NSTATE / 4 / BLOCK)  // 16

// One block per batch row. Thread t handles float4 chunks n4 = k*256 + t,
// i.e. elements n = 4*n4 + i.  Bit structure of n:
//   bits 0..1  = i        (inside float4)   -> qubits 13,12 : compile-time +/- combos
//   bits 2..9  = t        (thread index)    -> qubits 11..4 : per-thread fixed sign on S
//   bits 10..13= k        (k-loop index)    -> qubits 3..0  : signed accumulators
//
// KEY CHANGE vs prev round: partial unroll (2 k-steps / body = 4 loads, 16 dest
// VGPRs) instead of full 16-way unroll (32 loads, 128+ dest VGPRs -> spill to
// scratch + occupancy collapse; measured 1.08 TB/s). Target: <=64 VGPR, 8
// waves/SIMD, ~4 loads in flight per wave — Little's law needs only ~2.3 KB
// in flight per SIMD for 6.3 TB/s; this gives ~32 KB.
__global__ __launch_bounds__(BLOCK) void meas_kernel(const float* __restrict__ sr,
                                                     const float* __restrict__ si,
                                                     float* __restrict__ out) {
    const int b = blockIdx.x;
    const int t = threadIdx.x;
    const float4* sr4 = (const float4*)(sr + (size_t)b * NSTATE);
    const float4* si4 = (const float4*)(si + (size_t)b * NSTATE);

    float acc13 = 0.f, acc12 = 0.f, S = 0.f;
    float acc0 = 0.f, acc1 = 0.f, acc2 = 0.f, acc3 = 0.f;

#pragma unroll 1
    for (int k = 0; k < K_ITERS; k += 2) {
        const int n4a = k * BLOCK + t;
        const int n4b = n4a + BLOCK;
        const float4 a0 = sr4[n4a];
        const float4 c0 = si4[n4a];
        const float4 a1 = sr4[n4b];
        const float4 c1 = si4[n4b];

        const float p00 = a0.x * a0.x + c0.x * c0.x;
        const float p01 = a0.y * a0.y + c0.y * c0.y;
        const float p02 = a0.z * a0.z + c0.z * c0.z;
        const float p03 = a0.w * a0.w + c0.w * c0.w;
        const float p10 = a1.x * a1.x + c1.x * c1.x;
        const float p11 = a1.y * a1.y + c1.y * c1.y;
        const float p12 = a1.z * a1.z + c1.z * c1.z;
        const float p13 = a1.w * a1.w + c1.w * c1.w;

        // qubit 13 (bit0 of n): + - + -
        acc13 += (p00 - p01) + (p02 - p03) + (p10 - p11) + (p12 - p13);
        // qubit 12 (bit1 of n): + + - -
        acc12 += (p00 + p01) - (p02 + p03) + (p10 + p11) - (p12 + p13);

        const float sum0 = (p00 + p01) + (p02 + p03);
        const float sum1 = (p10 + p11) + (p12 + p13);
        const float s01  = sum0 + sum1;

        S    += s01;
        // qubit 3: bit0 of k — k even/odd inside body: compile-time
        acc3 += sum0 - sum1;
        // qubits 2..0: bits 1..3 of k — uniform per body, cndmask select
        acc2 += (k & 2) ? -s01 : s01;
        acc1 += (k & 4) ? -s01 : s01;
        acc0 += (k & 8) ? -s01 : s01;
    }

    // Per-thread contribution for every qubit; all become PLAIN sums over the block.
    float v[NQ];
    v[0] = acc0; v[1] = acc1; v[2] = acc2; v[3] = acc3;
#pragma unroll
    for (int q = 4; q <= 11; ++q) {
        // qubit q: sign = (-1)^{bit (11-q) of t}
        v[q] = ((t >> (11 - q)) & 1) ? -S : S;
    }
    v[12] = acc12; v[13] = acc13;

    // Wave(64)-level shuffle reduction of all 14 values.
#pragma unroll
    for (int q = 0; q < NQ; ++q) {
        float x = v[q];
#pragma unroll
        for (int off = 32; off > 0; off >>= 1)
            x += __shfl_down(x, off, 64);
        v[q] = x;
    }

    __shared__ float red[BLOCK / 64][NQ];
    const int wave = t >> 6;
    const int lane = t & 63;
    if (lane == 0) {
#pragma unroll
        for (int q = 0; q < NQ; ++q) red[wave][q] = v[q];
    }
    __syncthreads();
    if (t < NQ) {
        out[(size_t)b * NQ + t] = red[0][t] + red[1][t] + red[2][t] + red[3][t];
    }
}

extern "C" void kernel_launch(void* const* d_in, const int* in_sizes, int n_in,
                              void* d_out, int out_size, void* d_ws, size_t ws_size,
                              hipStream_t stream) {
    const float* sr = (const float*)d_in[0];
    const float* si = (const float*)d_in[1];
    float* out = (float*)d_out;
    const int batch = in_sizes[0] / NSTATE;  // 4096
    meas_kernel<<<dim3(batch), dim3(BLOCK), 0, stream>>>(sr, si, out);
}

// Round 4
// 466.001 us; speedup vs baseline: 1.0736x; 1.0736x over previous
//
#include <hip/hip_runtime.h>

#define NQ      14
#define NSTATE  16384   // 2^14
#define BLOCK   256
#define K_ITERS (NSTATE / 4 / BLOCK)  // 16
#define J_ITERS (K_ITERS / 4)         // 4 bodies, 4 k-steps each

// Native vector type: __builtin_nontemporal_load requires a real vector, not
// HIP's struct-based float4.
typedef float vf4 __attribute__((ext_vector_type(4)));

// One block per batch row. Thread t handles float4 chunks n4 = k*256 + t,
// i.e. elements n = 4*n4 + i.  Bit structure of n:
//   bits 0..1  = i   (inside float4)  -> qubits 13,12 : compile-time +/- combos
//   bits 2..9  = t   (thread index)   -> qubits 11..4 : per-thread fixed sign on S
//   bits 10..11= low bits of k        -> qubits 3,2   : compile-time within body
//   bits 12..13= j   (body index)     -> qubits 1,0   : runtime cndmask, 1x/body
//
// R2 post-mortem: top-5 rocprof dispatches are all 162 µs harness poison fills;
// meas_kernel < 162 µs, and dur_us(~500) carries ~330 µs fixed harness traffic.
// This round: 8 loads in flight/wave (8 KiB), nontemporal (read-once stream,
// 512 MiB > L3), VGPR ~70 -> 8 waves/SIMD. If dur_us doesn't move, kernel was
// already BW-saturated.
__global__ __launch_bounds__(BLOCK) void meas_kernel(const float* __restrict__ sr,
                                                     const float* __restrict__ si,
                                                     float* __restrict__ out) {
    const int b = blockIdx.x;
    const int t = threadIdx.x;
    const vf4* sr4 = (const vf4*)(sr + (size_t)b * NSTATE);
    const vf4* si4 = (const vf4*)(si + (size_t)b * NSTATE);

    float acc13 = 0.f, acc12 = 0.f, S = 0.f;
    float acc0 = 0.f, acc1 = 0.f, acc2 = 0.f, acc3 = 0.f;

#pragma unroll 1
    for (int j = 0; j < J_ITERS; ++j) {
        const int base = (j * 4) * BLOCK + t;
        // Issue all 8 loads up front (8 KiB in flight per wave).
        const vf4 a0 = __builtin_nontemporal_load(&sr4[base + 0 * BLOCK]);
        const vf4 c0 = __builtin_nontemporal_load(&si4[base + 0 * BLOCK]);
        const vf4 a1 = __builtin_nontemporal_load(&sr4[base + 1 * BLOCK]);
        const vf4 c1 = __builtin_nontemporal_load(&si4[base + 1 * BLOCK]);
        const vf4 a2 = __builtin_nontemporal_load(&sr4[base + 2 * BLOCK]);
        const vf4 c2 = __builtin_nontemporal_load(&si4[base + 2 * BLOCK]);
        const vf4 a3 = __builtin_nontemporal_load(&sr4[base + 3 * BLOCK]);
        const vf4 c3 = __builtin_nontemporal_load(&si4[base + 3 * BLOCK]);

        // Per-k probability quads.
        const float p00 = a0.x * a0.x + c0.x * c0.x;
        const float p01 = a0.y * a0.y + c0.y * c0.y;
        const float p02 = a0.z * a0.z + c0.z * c0.z;
        const float p03 = a0.w * a0.w + c0.w * c0.w;
        const float p10 = a1.x * a1.x + c1.x * c1.x;
        const float p11 = a1.y * a1.y + c1.y * c1.y;
        const float p12 = a1.z * a1.z + c1.z * c1.z;
        const float p13 = a1.w * a1.w + c1.w * c1.w;
        const float p20 = a2.x * a2.x + c2.x * c2.x;
        const float p21 = a2.y * a2.y + c2.y * c2.y;
        const float p22 = a2.z * a2.z + c2.z * c2.z;
        const float p23 = a2.w * a2.w + c2.w * c2.w;
        const float p30 = a3.x * a3.x + c3.x * c3.x;
        const float p31 = a3.y * a3.y + c3.y * c3.y;
        const float p32 = a3.z * a3.z + c3.z * c3.z;
        const float p33 = a3.w * a3.w + c3.w * c3.w;

        // qubit 13 (bit0 of n): + - + - within each float4
        acc13 += ((p00 - p01) + (p02 - p03)) + ((p10 - p11) + (p12 - p13))
               + ((p20 - p21) + (p22 - p23)) + ((p30 - p31) + (p32 - p33));
        // qubit 12 (bit1 of n): + + - -
        acc12 += ((p00 + p01) - (p02 + p03)) + ((p10 + p11) - (p12 + p13))
               + ((p20 + p21) - (p22 + p23)) + ((p30 + p31) - (p32 + p33));

        const float P0 = (p00 + p01) + (p02 + p03);
        const float P1 = (p10 + p11) + (p12 + p13);
        const float P2 = (p20 + p21) + (p22 + p23);
        const float P3 = (p30 + p31) + (p32 + p33);

        // qubit 3 (bit0 of k): compile-time within body
        acc3 += (P0 - P1) + (P2 - P3);
        // qubit 2 (bit1 of k): compile-time within body
        acc2 += (P0 + P1) - (P2 + P3);

        const float S4 = (P0 + P1) + (P2 + P3);
        S += S4;
        // qubits 1,0: bits 2,3 of k = bits 0,1 of j — one cndmask each per body
        acc1 += (j & 1) ? -S4 : S4;
        acc0 += (j & 2) ? -S4 : S4;
    }

    // Per-thread contribution for every qubit; all become PLAIN sums over the block.
    float v[NQ];
    v[0] = acc0; v[1] = acc1; v[2] = acc2; v[3] = acc3;
#pragma unroll
    for (int q = 4; q <= 11; ++q) {
        // qubit q: sign = (-1)^{bit (11-q) of t}
        v[q] = ((t >> (11 - q)) & 1) ? -S : S;
    }
    v[12] = acc12; v[13] = acc13;

    // Wave(64)-level shuffle reduction of all 14 values.
#pragma unroll
    for (int q = 0; q < NQ; ++q) {
        float x = v[q];
#pragma unroll
        for (int off = 32; off > 0; off >>= 1)
            x += __shfl_down(x, off, 64);
        v[q] = x;
    }

    __shared__ float red[BLOCK / 64][NQ];
    const int wave = t >> 6;
    const int lane = t & 63;
    if (lane == 0) {
#pragma unroll
        for (int q = 0; q < NQ; ++q) red[wave][q] = v[q];
    }
    __syncthreads();
    if (t < NQ) {
        out[(size_t)b * NQ + t] = red[0][t] + red[1][t] + red[2][t] + red[3][t];
    }
}

extern "C" void kernel_launch(void* const* d_in, const int* in_sizes, int n_in,
                              void* d_out, int out_size, void* d_ws, size_t ws_size,
                              hipStream_t stream) {
    const float* sr = (const float*)d_in[0];
    const float* si = (const float*)d_in[1];
    float* out = (float*)d_out;
    const int batch = in_sizes[0] / NSTATE;  // 4096
    meas_kernel<<<dim3(batch), dim3(BLOCK), 0, stream>>>(sr, si, out);
}